// Round 1
// 141.695 us; speedup vs baseline: 1.0050x; 1.0050x over previous
//
#include <hip/hip_runtime.h>

// Row-wise cosine hinge loss.
//   j = (i + 1 + neg_idx[i]) % B
//   hinge_i = relu(1 - cos(t_i, o_i) + cos(t_j, o_i))
//   out = sum_i hinge_i / B
//
// Wave-per-row, STATIC 4-row depth-2 register pipeline:
//  - all 4 gather indices (negidx) loaded at kernel entry -> no dependent
//    scalar load on any row's issue path (was ~200-900 cy x4 per wave)
//  - two named RowBufs alternate A/B -> no runtime-indexed buffer (scratch
//    risk) and no cur=nxt register copies
//  - row i+1's 12 float4 loads are in flight while row i is consumed,
//    keeping ~24 KB/wave outstanding through the consume phase.

#define EPS 1e-6f

typedef float f4 __attribute__((ext_vector_type(4)));

// VALU-pipe wave reduction via DPP; lane 63 holds the 64-lane sum.
#define DPP_STEP(x, ctrl, rm, bm)                                             \
    x += __int_as_float(__builtin_amdgcn_update_dpp(                          \
        0, __float_as_int(x), (ctrl), (rm), (bm), true))

__device__ __forceinline__ float dpp_wave_sum(float x) {
    DPP_STEP(x, 0x111, 0xf, 0xf);  // row_shr:1
    DPP_STEP(x, 0x112, 0xf, 0xf);  // row_shr:2
    DPP_STEP(x, 0x114, 0xf, 0xe);  // row_shr:4
    DPP_STEP(x, 0x118, 0xf, 0xc);  // row_shr:8
    DPP_STEP(x, 0x142, 0xa, 0xf);  // row_bcast:15
    DPP_STEP(x, 0x143, 0xc, 0xf);  // row_bcast:31
    return x;                      // valid in lane 63
}

struct RowBuf {
    f4 o[4], t[4], n[4];
};

__device__ __forceinline__ void issue_loads(RowBuf& rb,
                                            const float* __restrict__ outm,
                                            const float* __restrict__ tgt,
                                            int i, int j, int lane, int D) {
    const f4* o4 = (const f4*)(outm + (size_t)i * D);
    const f4* t4 = (const f4*)(tgt  + (size_t)i * D);
    const f4* n4 = (const f4*)(tgt  + (size_t)j * D);
#pragma unroll
    for (int k = 0; k < 4; ++k)
        rb.o[k] = __builtin_nontemporal_load(&o4[lane + 64 * k]);  // single-use stream
#pragma unroll
    for (int k = 0; k < 4; ++k) rb.t[k] = t4[lane + 64 * k];       // keep in L3 for gathers
#pragma unroll
    for (int k = 0; k < 4; ++k) rb.n[k] = n4[lane + 64 * k];
}

// Returns this row's hinge value (valid in lane 63; other lanes garbage).
__device__ __forceinline__ float consume(const RowBuf& rb) {
    float dto = 0.f, dno = 0.f, oo = 0.f, tt = 0.f, nn = 0.f;
#pragma unroll
    for (int k = 0; k < 4; ++k) {
        dto += rb.o[k].x*rb.t[k].x + rb.o[k].y*rb.t[k].y + rb.o[k].z*rb.t[k].z + rb.o[k].w*rb.t[k].w;
        dno += rb.o[k].x*rb.n[k].x + rb.o[k].y*rb.n[k].y + rb.o[k].z*rb.n[k].z + rb.o[k].w*rb.n[k].w;
        oo  += rb.o[k].x*rb.o[k].x + rb.o[k].y*rb.o[k].y + rb.o[k].z*rb.o[k].z + rb.o[k].w*rb.o[k].w;
        tt  += rb.t[k].x*rb.t[k].x + rb.t[k].y*rb.t[k].y + rb.t[k].z*rb.t[k].z + rb.t[k].w*rb.t[k].w;
        nn  += rb.n[k].x*rb.n[k].x + rb.n[k].y*rb.n[k].y + rb.n[k].z*rb.n[k].z + rb.n[k].w*rb.n[k].w;
    }
    dto = dpp_wave_sum(dto);
    dno = dpp_wave_sum(dno);
    oo  = dpp_wave_sum(oo);
    tt  = dpp_wave_sum(tt);
    nn  = dpp_wave_sum(nn);
    float no = sqrtf(oo);
    float h  = 1.f - dto / fmaxf(sqrtf(tt) * no, EPS)
                   + dno / fmaxf(sqrtf(nn) * no, EPS);
    return fmaxf(h, 0.f);
}

__global__ __launch_bounds__(256, 4) void hinge_cos_kernel(
    const float* __restrict__ outm,   // [B, D]
    const float* __restrict__ tgt,    // [B, D]
    const int*   __restrict__ negidx, // [B]
    float* __restrict__ res,          // [1] scalar (pre-zeroed)
    int B, int D, float invB) {

    const int lane  = threadIdx.x & 63;
    const int wave  = threadIdx.x >> 6;
    const int wpb   = blockDim.x >> 6;           // 4
    const int gwave = blockIdx.x * wpb + wave;
    const int nwav  = gridDim.x * wpb;

    // Static 4-row assignment: this wave owns rows gwave + k*nwav, k=0..3.
    const int i0 = gwave;
    const int i1 = i0 + nwav;
    const int i2 = i1 + nwav;
    const int i3 = i2 + nwav;
    const bool v0 = i0 < B, v1 = i1 < B, v2 = i2 < B, v3 = i3 < B;

    // Hoist ALL gather indices: 4 independent loads, one wait, zero
    // dependent loads on the per-row issue path.
    int g0 = v0 ? negidx[i0] : 0;
    int g1 = v1 ? negidx[i1] : 0;
    int g2 = v2 ? negidx[i2] : 0;
    int g3 = v3 ? negidx[i3] : 0;
    int j0 = i0 + 1 + g0; if (j0 >= B) j0 -= B;
    int j1 = i1 + 1 + g1; if (j1 >= B) j1 -= B;
    int j2 = i2 + 1 + g2; if (j2 >= B) j2 -= B;
    int j3 = i3 + 1 + g3; if (j3 >= B) j3 -= B;

    float acc = 0.f;                              // per-wave hinge sum (lane 63)
    RowBuf bufA, bufB;                            // named: never runtime-indexed

    if (v0) issue_loads(bufA, outm, tgt, i0, j0, lane, D);
    if (v1) issue_loads(bufB, outm, tgt, i1, j1, lane, D);
    if (v0) { float h = consume(bufA); if (lane == 63) acc += h; }
    if (v2) issue_loads(bufA, outm, tgt, i2, j2, lane, D);
    if (v1) { float h = consume(bufB); if (lane == 63) acc += h; }
    if (v3) issue_loads(bufB, outm, tgt, i3, j3, lane, D);
    if (v2) { float h = consume(bufA); if (lane == 63) acc += h; }
    if (v3) { float h = consume(bufB); if (lane == 63) acc += h; }

    // Block-level: lane 63 of each wave holds its partial; one atomic per block.
    __shared__ float red[4];
    if (lane == 63) red[wave] = acc;
    __syncthreads();
    if (threadIdx.x == 0) {
        float s = 0.f;
#pragma unroll
        for (int w = 0; w < 4; ++w) s += red[w];
        atomicAdd(res, s * invB);
    }
}

extern "C" void kernel_launch(void* const* d_in, const int* in_sizes, int n_in,
                              void* d_out, int out_size, void* d_ws, size_t ws_size,
                              hipStream_t stream) {
    const float* outm   = (const float*)d_in[0];
    const float* tgt    = (const float*)d_in[1];
    const int*   negidx = (const int*)d_in[2];
    float* res = (float*)d_out;

    const int B = in_sizes[2];
    const int D = in_sizes[0] / B;

    (void)hipMemsetAsync(res, 0, sizeof(float), stream);

    // Exactly 4 rows per wave: nwav = ceil(B/4), 4 waves per 256-thr block.
    const int nwav   = (B + 3) / 4;
    const int blocks = (nwav + 3) / 4;
    hinge_cos_kernel<<<blocks, 256, 0, stream>>>(outm, tgt, negidx, res, B, D,
                                                 1.0f / (float)B);
}